// Round 3
// baseline (375.914 us; speedup 1.0000x reference)
//
#include <hip/hip_runtime.h>
#include <stdint.h>

#define SEQ 4096
#define DIM 128
#define NHEADS 8
#define HDK 16

typedef __bf16 bf16x8 __attribute__((ext_vector_type(8)));
typedef float f32x16 __attribute__((ext_vector_type(16)));
typedef float f32x4 __attribute__((ext_vector_type(4)));
typedef unsigned uint2v __attribute__((ext_vector_type(2)));
typedef unsigned uint4v __attribute__((ext_vector_type(4)));

__device__ inline unsigned short f2bf(float x) {
  unsigned u = __builtin_bit_cast(unsigned, x);
  u = (u + 0x7FFFu + ((u >> 16) & 1u)) >> 16;
  return (unsigned short)u;
}
__device__ inline unsigned pkbf(float lo, float hi) {
  return (unsigned)f2bf(lo) | ((unsigned)f2bf(hi) << 16);
}

// ---------------- kernel 0: mask dtype probe -------------------------------
__global__ void k_detect(const unsigned* __restrict__ mw, int* __restrict__ flag) {
  if (threadIdx.x == 0) {
    int words = 1;
    for (int i = 0; i < 32; ++i) {
      unsigned w = mw[i];
      if (!(w == 0u || w == 1u || w == 0x3F800000u)) words = 0;
    }
    *flag = words;
  }
}

// ---------------- kernel 1: input projections ------------------------------
// mat 0: Qp[b][n][h*16+k] = 0.25*log2(e) * (q @ Wq_h)
// mat 1: Kp[b][n][h*16+k] = (h @ Wk_h)
// mat 2: Vt[b][h*16+v][n] = (h @ Wv_h)^T
__global__ __launch_bounds__(256) void k_proj(
    const float* __restrict__ qin, const float* __restrict__ hin,
    const float* __restrict__ Wq, const float* __restrict__ Wk, const float* __restrict__ Wv,
    unsigned short* __restrict__ Qp, unsigned short* __restrict__ Kp,
    unsigned short* __restrict__ Vt) {
  __shared__ float Wl[128][128];   // Wl[i][c], c = h*16+k
  __shared__ float inl[8][128];
  const int mat = blockIdx.y;
  const float* in = (mat == 0) ? qin : hin;
  const float* W  = (mat == 0) ? Wq : (mat == 1 ? Wk : Wv);
  for (int e = threadIdx.x; e < 128 * 128; e += 256) {
    int i = e >> 7, c = e & 127;   // W shape (8,128,16): [h][i][k]
    Wl[i][c] = W[((size_t)((c >> 4) * 128 + i)) * 16 + (c & 15)];
  }
  const int r  = threadIdx.x >> 5;
  const int cg = (threadIdx.x & 31) << 2;
  const size_t rb = (size_t)blockIdx.x * 64;
  const float SCALE_Q = 0.25f * 1.4426950408889634f;  // norm * log2(e)
  for (int pass = 0; pass < 8; ++pass) {
    __syncthreads();
    size_t row0 = rb + pass * 8;
    for (int e = threadIdx.x; e < 8 * 128; e += 256)
      inl[e >> 7][e & 127] = in[(row0 + (e >> 7)) * 128 + (e & 127)];
    __syncthreads();
    f32x4 acc = {0.f, 0.f, 0.f, 0.f};
    #pragma unroll 8
    for (int i = 0; i < 128; ++i) {
      float a = inl[r][i];
      acc += a * *(const f32x4*)&Wl[i][cg];
    }
    size_t grow = row0 + r;
    if (mat == 0) {
      uint2v o = { pkbf(acc[0] * SCALE_Q, acc[1] * SCALE_Q),
                   pkbf(acc[2] * SCALE_Q, acc[3] * SCALE_Q) };
      *(uint2v*)(Qp + grow * DIM + cg) = o;
    } else if (mat == 1) {
      uint2v o = { pkbf(acc[0], acc[1]), pkbf(acc[2], acc[3]) };
      *(uint2v*)(Kp + grow * DIM + cg) = o;
    } else {
      size_t b = grow >> 12, n = grow & 4095;
      #pragma unroll
      for (int j = 0; j < 4; ++j)
        Vt[(b * DIM + cg + j) * SEQ + n] = f2bf(acc[j]);
    }
  }
}

// ---------------- kernel 2: fused flash attention --------------------------
// 256 blocks = B*(S/32); 512 thr = 8 waves = 8 heads.
// QK^T swapped: st = mfma(A=K_tile, B=Q^T) -> st[r] = S[q][kv=crow(r,hi)], q=lane&31.
// PV transposed: oacc = mfma(A=V^T, B=P^T) -> heads^T[channel=crow(r,hi)][q=lane&31].
// => softmax state (m, lsum) AND O-rescale are pure per-lane scalars.
__global__ __launch_bounds__(512) void k_flash(
    const unsigned short* __restrict__ Qp, const unsigned short* __restrict__ Kp,
    const unsigned short* __restrict__ Vt, const void* __restrict__ maskp,
    const int* __restrict__ flagp, float* __restrict__ heads) {
  __shared__ unsigned mbits[2][32];     // packed mask bits per q row (double buf)
  const int tid  = threadIdx.x;
  const int wv   = tid >> 6;
  const int lane = tid & 63;
  const int q    = lane & 31;
  const int hi   = lane >> 5;
  const int h    = wv;
  const int b    = blockIdx.x >> 7;
  const int qb   = (blockIdx.x & 127) << 5;
  const int wordmode = *flagp;

  const bf16x8 qfrag =
      *(const bf16x8*)(Qp + ((size_t)b * SEQ + qb + q) * DIM + h * HDK + hi * 8);
  const unsigned short* kptr = Kp + ((size_t)b * SEQ) * DIM + h * HDK + hi * 8;
  const unsigned short* vptr = Vt + ((size_t)b * DIM + h * HDK + q) * SEQ + hi * 8;
  const bool vval = q < 16;   // A-operand guard only: V channels 16..31 are zero

  const unsigned*      mw = (const unsigned*)maskp;
  const unsigned char* m8 = (const unsigned char*)maskp;
  const size_t mrowbase = (size_t)b * SEQ + qb;

  f32x16 oacc = {};           // heads^T: row = channel crow(r,hi), col = own q
  float m = -1e38f, lsum = 0.f;

  for (int kt = 0; kt < SEQ / 32; ++kt) {
    const int kvb = kt << 5;
    const int bf  = kt & 1;
    // ---- stage 32q x 32kv mask tile as 32 bitmasks (each elem read once)
    #pragma unroll
    for (int j = 0; j < 2; ++j) {
      int e = j * 512 + tid;
      int eq = e >> 5, ekv = e & 31;
      size_t gi = (mrowbase + eq) * SEQ + (size_t)(kvb + ekv);
      bool pred = wordmode ? (mw[gi] != 0u) : (m8[gi] != 0);
      unsigned long long bal = __ballot(pred);
      if (lane == 0) {
        int rowq = (j << 4) + (wv << 1);
        mbits[bf][rowq]     = (unsigned)bal;
        mbits[bf][rowq + 1] = (unsigned)(bal >> 32);
      }
    }
    __syncthreads();

    // ---- scores: S^T tile, column q per lane
    const bf16x8 kfrag = *(const bf16x8*)(kptr + (size_t)(kvb + q) * DIM);
    f32x16 z16 = {};
    f32x16 st = __builtin_amdgcn_mfma_f32_32x32x16_bf16(kfrag, qfrag, z16, 0, 0, 0);

    const unsigned mrow = mbits[bf][q];
    float s[16];
    #pragma unroll
    for (int r = 0; r < 16; ++r) {
      const int kv = (r & 3) + 8 * (r >> 2) + (hi << 2);
      s[r] = ((mrow >> kv) & 1u) ? -3.0e38f : st[r];
    }
    // ---- online softmax in log2 domain (scale folded into Q)
    float tmax = s[0];
    #pragma unroll
    for (int r = 1; r < 16; ++r) tmax = fmaxf(tmax, s[r]);
    tmax = fmaxf(tmax, __shfl_xor(tmax, 32));

    const float newm = fmaxf(m, tmax);
    const float fs = exp2f(m - newm);   // per-lane scalar rescale (col = own q)
    m = newm;
    lsum *= fs;
    #pragma unroll
    for (int r = 0; r < 16; ++r) oacc[r] *= fs;

    float p[16], ts = 0.f;
    #pragma unroll
    for (int r = 0; r < 16; ++r) { p[r] = exp2f(s[r] - m); ts += p[r]; }
    lsum += ts + __shfl_xor(ts, 32);

    // ---- PV: heads^T += V^T_slice * P^T_slice  (two K=16 slices)
    #pragma unroll
    for (int sl = 0; sl < 2; ++sl) {
      // own packed words (kv_local within slice): hi=0: (0,1),(2,3),(8,9),(10,11)
      //                                           hi=1: (4,5),(6,7),(12,13),(14,15)
      unsigned a0 = pkbf(p[8 * sl + 0], p[8 * sl + 1]);
      unsigned a1 = pkbf(p[8 * sl + 2], p[8 * sl + 3]);
      unsigned b0 = pkbf(p[8 * sl + 4], p[8 * sl + 5]);
      unsigned b1 = pkbf(p[8 * sl + 6], p[8 * sl + 7]);
      unsigned pa0 = (unsigned)__shfl_xor((int)a0, 32);
      unsigned pa1 = (unsigned)__shfl_xor((int)a1, 32);
      unsigned pb0 = (unsigned)__shfl_xor((int)b0, 32);
      unsigned pb1 = (unsigned)__shfl_xor((int)b1, 32);
      // B-frag: lane needs kv_local k = hi*8 + e
      uint4v w = { hi ? pb0 : a0, hi ? pb1 : a1, hi ? b0 : pa0, hi ? b1 : pa1 };
      bf16x8 pfrag = __builtin_bit_cast(bf16x8, w);
      bf16x8 vfrag = {};
      if (vval) vfrag = *(const bf16x8*)(vptr + kvb + sl * 16);
      oacc = __builtin_amdgcn_mfma_f32_32x32x16_bf16(vfrag, pfrag, oacc, 0, 0, 0);
    }
  }

  // ---- epilogue: ALL lanes store their own query column q (fix vs r1!)
  // lane (q,hi): channels 4hi+0..3 = oacc[0..3], channels 8+4hi+0..3 = oacc[4..7]
  const float rinv = lsum > 0.f ? 1.0f / lsum : 0.f;
  float* hp = heads + ((size_t)b * SEQ + qb + q) * DIM + h * HDK;
  f32x4 w0 = { oacc[0] * rinv, oacc[1] * rinv, oacc[2] * rinv, oacc[3] * rinv };
  f32x4 w1 = { oacc[4] * rinv, oacc[5] * rinv, oacc[6] * rinv, oacc[7] * rinv };
  *(f32x4*)(hp + 4 * hi)     = w0;
  *(f32x4*)(hp + 8 + 4 * hi) = w1;
}

// ---------------- kernel 3: output projection ------------------------------
__global__ __launch_bounds__(256) void k_oproj(
    const float* __restrict__ heads, const float* __restrict__ Wo,
    float* __restrict__ out) {
  __shared__ float Wl[128][128];
  __shared__ float inl[8][128];
  for (int e = threadIdx.x; e < 128 * 128; e += 256) Wl[e >> 7][e & 127] = Wo[e];
  const int r  = threadIdx.x >> 5;
  const int cg = (threadIdx.x & 31) << 2;
  const size_t rb = (size_t)blockIdx.x * 64;
  for (int pass = 0; pass < 8; ++pass) {
    __syncthreads();
    size_t row0 = rb + pass * 8;
    for (int e = threadIdx.x; e < 8 * 128; e += 256)
      inl[e >> 7][e & 127] = heads[(row0 + (e >> 7)) * 128 + (e & 127)];
    __syncthreads();
    f32x4 acc = {0.f, 0.f, 0.f, 0.f};
    #pragma unroll 8
    for (int i = 0; i < 128; ++i) acc += inl[r][i] * *(const f32x4*)&Wl[i][cg];
    *(f32x4*)(out + (row0 + r) * 128 + cg) = acc;
  }
}

// ---------------- launch ---------------------------------------------------
extern "C" void kernel_launch(void* const* d_in, const int* in_sizes, int n_in,
                              void* d_out, int out_size, void* d_ws, size_t ws_size,
                              hipStream_t stream) {
  const float* qin = (const float*)d_in[0];
  const float* hin = (const float*)d_in[1];
  const void* mask = d_in[2];
  const float* Wq  = (const float*)d_in[3];
  const float* Wk  = (const float*)d_in[4];
  const float* Wv  = (const float*)d_in[5];
  const float* Wo  = (const float*)d_in[6];
  float* out = (float*)d_out;
  char* ws = (char*)d_ws;
  int* flag = (int*)ws;
  const size_t MAT = (size_t)2 * SEQ * DIM;   // elems per bf16 matrix
  unsigned short* Qp    = (unsigned short*)(ws + 1024);
  unsigned short* Kp    = Qp + MAT;
  unsigned short* Vt    = Kp + MAT;
  float*          heads = (float*)(Vt + MAT);  // f32, 4 MB

  k_detect<<<1, 64, 0, stream>>>((const unsigned*)mask, flag);
  k_proj<<<dim3(128, 3), 256, 0, stream>>>(qin, hin, Wq, Wk, Wv, Qp, Kp, Vt);
  k_flash<<<256, 512, 0, stream>>>(Qp, Kp, Vt, mask, flag, heads);
  k_oproj<<<128, 256, 0, stream>>>(heads, Wo, out);
}

// Round 4
// 355.411 us; speedup vs baseline: 1.0577x; 1.0577x over previous
//
#include <hip/hip_runtime.h>
#include <stdint.h>

#define SEQ 4096
#define DIM 128
#define NHEADS 8
#define HDK 16

typedef __bf16 bf16x8 __attribute__((ext_vector_type(8)));
typedef float f32x16 __attribute__((ext_vector_type(16)));
typedef float f32x4 __attribute__((ext_vector_type(4)));
typedef unsigned uint2v __attribute__((ext_vector_type(2)));
typedef unsigned uint4v __attribute__((ext_vector_type(4)));

__device__ inline unsigned short f2bf(float x) {
  unsigned u = __builtin_bit_cast(unsigned, x);
  u = (u + 0x7FFFu + ((u >> 16) & 1u)) >> 16;
  return (unsigned short)u;
}
__device__ inline unsigned pkbf(float lo, float hi) {
  return (unsigned)f2bf(lo) | ((unsigned)f2bf(hi) << 16);
}

// ---------------- kernel 0: mask dtype probe -------------------------------
__global__ void k_detect(const unsigned* __restrict__ mw, int* __restrict__ flag) {
  if (threadIdx.x == 0) {
    int words = 1;
    for (int i = 0; i < 32; ++i) {
      unsigned w = mw[i];
      if (!(w == 0u || w == 1u || w == 0x3F800000u)) words = 0;
    }
    *flag = words;
  }
}

// ---------------- kernel 1: input projections ------------------------------
__global__ __launch_bounds__(256) void k_proj(
    const float* __restrict__ qin, const float* __restrict__ hin,
    const float* __restrict__ Wq, const float* __restrict__ Wk, const float* __restrict__ Wv,
    unsigned short* __restrict__ Qp, unsigned short* __restrict__ Kp,
    unsigned short* __restrict__ Vt) {
  __shared__ float Wl[128][128];   // Wl[i][c], c = h*16+k
  __shared__ float inl[8][128];
  const int mat = blockIdx.y;
  const float* in = (mat == 0) ? qin : hin;
  const float* W  = (mat == 0) ? Wq : (mat == 1 ? Wk : Wv);
  for (int e = threadIdx.x; e < 128 * 128; e += 256) {
    int i = e >> 7, c = e & 127;   // W shape (8,128,16): [h][i][k]
    Wl[i][c] = W[((size_t)((c >> 4) * 128 + i)) * 16 + (c & 15)];
  }
  const int r  = threadIdx.x >> 5;
  const int cg = (threadIdx.x & 31) << 2;
  const size_t rb = (size_t)blockIdx.x * 64;
  const float SCALE_Q = 0.25f * 1.4426950408889634f;  // norm * log2(e)
  for (int pass = 0; pass < 8; ++pass) {
    __syncthreads();
    size_t row0 = rb + pass * 8;
    for (int e = threadIdx.x; e < 8 * 128; e += 256)
      inl[e >> 7][e & 127] = in[(row0 + (e >> 7)) * 128 + (e & 127)];
    __syncthreads();
    f32x4 acc = {0.f, 0.f, 0.f, 0.f};
    #pragma unroll 8
    for (int i = 0; i < 128; ++i) {
      float a = inl[r][i];
      acc += a * *(const f32x4*)&Wl[i][cg];
    }
    size_t grow = row0 + r;
    if (mat == 0) {
      uint2v o = { pkbf(acc[0] * SCALE_Q, acc[1] * SCALE_Q),
                   pkbf(acc[2] * SCALE_Q, acc[3] * SCALE_Q) };
      *(uint2v*)(Qp + grow * DIM + cg) = o;
    } else if (mat == 1) {
      uint2v o = { pkbf(acc[0], acc[1]), pkbf(acc[2], acc[3]) };
      *(uint2v*)(Kp + grow * DIM + cg) = o;
    } else {
      size_t b = grow >> 12, n = grow & 4095;
      #pragma unroll
      for (int j = 0; j < 4; ++j)
        Vt[(b * DIM + cg + j) * SEQ + n] = f2bf(acc[j]);
    }
  }
}

// ---------------- kernel 2: fused flash attention, split-K -----------------
// grid = 256*NS blocks; block = 8 waves = 8 heads; sp = blockIdx>>8 covers
// KV tiles [sp*NT, (sp+1)*NT).  Partials (unnormalized O^T, m, l) -> ws.
// Mask + K-frag are software-prefetched one tile ahead (registers), so the
// once-read mask stream's HBM latency hides under compute.
__global__ __launch_bounds__(512, 8) void k_flash(
    const unsigned short* __restrict__ Qp, const unsigned short* __restrict__ Kp,
    const unsigned short* __restrict__ Vt, const void* __restrict__ maskp,
    const int* __restrict__ flagp, float* __restrict__ parts,
    float* __restrict__ Mb, float* __restrict__ Lb, int NT) {
  __shared__ unsigned mbits[2][32];
  const int tid  = threadIdx.x;
  const int wv   = tid >> 6;
  const int lane = tid & 63;
  const int q    = lane & 31;
  const int hi   = lane >> 5;
  const int h    = wv;
  const int sp   = blockIdx.x >> 8;
  const int bqb  = blockIdx.x & 255;
  const int b    = bqb >> 7;
  const int qb   = (bqb & 127) << 5;
  const int kt0  = sp * NT;
  const int wordmode = *flagp;

  const bf16x8 qfrag =
      *(const bf16x8*)(Qp + ((size_t)b * SEQ + qb + q) * DIM + h * HDK + hi * 8);
  const unsigned short* kptr = Kp + ((size_t)b * SEQ) * DIM + h * HDK + hi * 8;
  const unsigned short* vptr = Vt + ((size_t)b * DIM + h * HDK + q) * SEQ + hi * 8;
  const bool vval = q < 16;   // A-operand guard: V channels 16..31 are zero

  const unsigned*      mw = (const unsigned*)maskp;
  const unsigned char* m8 = (const unsigned char*)maskp;
  const size_t mrowbase = (size_t)b * SEQ + qb;

  // ---- prefetch state: mask words (rows tid>>5 and 16+tid>>5) + K frag
  size_t gi0 = (mrowbase + (tid >> 5)) * SEQ + ((size_t)kt0 << 5) + (tid & 31);
  size_t gi1 = gi0 + (size_t)16 * SEQ;
  unsigned pv0, pv1;
  if (wordmode) { pv0 = mw[gi0]; pv1 = mw[gi1]; }
  else          { pv0 = m8[gi0]; pv1 = m8[gi1]; }
  bf16x8 kf = *(const bf16x8*)(kptr + (size_t)((kt0 << 5) + q) * DIM);

  f32x16 oacc = {};           // O^T: row = channel crow(r,hi), col = own q
  float m = -1e38f, lsum = 0.f;

  for (int t = 0; t < NT; ++t) {
    const int kvb = (kt0 + t) << 5;
    const int bf  = t & 1;
    // ---- ballot the prefetched mask words into packed row-bitmasks
    {
      unsigned long long bal = __ballot(pv0 != 0u);
      if (lane == 0) {
        mbits[bf][(wv << 1)]     = (unsigned)bal;
        mbits[bf][(wv << 1) + 1] = (unsigned)(bal >> 32);
      }
    }
    {
      unsigned long long bal = __ballot(pv1 != 0u);
      if (lane == 0) {
        mbits[bf][16 + (wv << 1)]     = (unsigned)bal;
        mbits[bf][16 + (wv << 1) + 1] = (unsigned)(bal >> 32);
      }
    }
    // ---- issue next tile's prefetch (mask + K) before the barrier
    const int adv = (t + 1 < NT) ? 32 : 0;
    gi0 += adv; gi1 += adv;
    if (wordmode) { pv0 = mw[gi0]; pv1 = mw[gi1]; }
    else          { pv0 = m8[gi0]; pv1 = m8[gi1]; }
    bf16x8 kfn = *(const bf16x8*)(kptr + (size_t)(kvb + adv + q) * DIM);
    __syncthreads();

    // ---- scores: S^T tile, column q per lane
    f32x16 z16 = {};
    f32x16 st = __builtin_amdgcn_mfma_f32_32x32x16_bf16(kf, qfrag, z16, 0, 0, 0);
    kf = kfn;

    const unsigned mrow = mbits[bf][q];
    float s[16];
    #pragma unroll
    for (int r = 0; r < 16; ++r) {
      const int kv = (r & 3) + 8 * (r >> 2) + (hi << 2);
      s[r] = ((mrow >> kv) & 1u) ? -3.0e38f : st[r];
    }
    // ---- online softmax in log2 domain (scale folded into Q)
    float tmax = s[0];
    #pragma unroll
    for (int r = 1; r < 16; ++r) tmax = fmaxf(tmax, s[r]);
    tmax = fmaxf(tmax, __shfl_xor(tmax, 32));

    const float newm = fmaxf(m, tmax);
    const float fs = exp2f(m - newm);   // per-lane scalar (col = own q)
    m = newm;
    lsum *= fs;
    #pragma unroll
    for (int r = 0; r < 16; ++r) oacc[r] *= fs;

    float p[16], ts = 0.f;
    #pragma unroll
    for (int r = 0; r < 16; ++r) { p[r] = exp2f(s[r] - m); ts += p[r]; }
    lsum += ts + __shfl_xor(ts, 32);

    // ---- PV: O^T += V^T_slice * P^T_slice  (two K=16 slices)
    #pragma unroll
    for (int sl = 0; sl < 2; ++sl) {
      unsigned a0 = pkbf(p[8 * sl + 0], p[8 * sl + 1]);
      unsigned a1 = pkbf(p[8 * sl + 2], p[8 * sl + 3]);
      unsigned b0 = pkbf(p[8 * sl + 4], p[8 * sl + 5]);
      unsigned b1 = pkbf(p[8 * sl + 6], p[8 * sl + 7]);
      unsigned pa0 = (unsigned)__shfl_xor((int)a0, 32);
      unsigned pa1 = (unsigned)__shfl_xor((int)a1, 32);
      unsigned pb0 = (unsigned)__shfl_xor((int)b0, 32);
      unsigned pb1 = (unsigned)__shfl_xor((int)b1, 32);
      uint4v w = { hi ? pb0 : a0, hi ? pb1 : a1, hi ? b0 : pa0, hi ? b1 : pa1 };
      bf16x8 pfrag = __builtin_bit_cast(bf16x8, w);
      bf16x8 vfrag = {};
      if (vval) vfrag = *(const bf16x8*)(vptr + kvb + sl * 16);
      oacc = __builtin_amdgcn_mfma_f32_32x32x16_bf16(vfrag, pfrag, oacc, 0, 0, 0);
    }
  }

  // ---- epilogue: unnormalized partial store; all lanes store own q column
  const size_t row = (size_t)b * SEQ + qb + q;
  float* hp = parts + ((size_t)sp * 2 * SEQ + row) * DIM + h * HDK;
  f32x4 w0 = { oacc[0], oacc[1], oacc[2], oacc[3] };
  f32x4 w1 = { oacc[4], oacc[5], oacc[6], oacc[7] };
  *(f32x4*)(hp + 4 * hi)     = w0;
  *(f32x4*)(hp + 8 + 4 * hi) = w1;
  if (hi == 0) {
    Mb[((size_t)sp * 2 * SEQ + row) * NHEADS + h] = m;
    Lb[((size_t)sp * 2 * SEQ + row) * NHEADS + h] = lsum;
  }
}

// ---------------- kernel 2b: split-K combine -------------------------------
__global__ __launch_bounds__(256) void k_comb(
    const float* __restrict__ parts, const float* __restrict__ Mb,
    const float* __restrict__ Lb, float* __restrict__ heads, int NS) {
  const size_t R = (size_t)2 * SEQ;
  const size_t row = (size_t)blockIdx.x * 8 + (threadIdx.x >> 5);
  const int cg = (threadIdx.x & 31) << 2;
  const int h  = cg >> 4;
  float mmax = -1e38f;
  for (int sp = 0; sp < NS; ++sp)
    mmax = fmaxf(mmax, Mb[(sp * R + row) * NHEADS + h]);
  float l = 0.f;
  f32x4 acc = {0.f, 0.f, 0.f, 0.f};
  for (int sp = 0; sp < NS; ++sp) {
    float w = exp2f(Mb[(sp * R + row) * NHEADS + h] - mmax);
    l += Lb[(sp * R + row) * NHEADS + h] * w;
    f32x4 p = *(const f32x4*)&parts[(sp * R + row) * DIM + cg];
    acc += p * w;
  }
  const float rinv = l > 0.f ? 1.0f / l : 0.f;
  acc *= rinv;
  *(f32x4*)&heads[row * DIM + cg] = acc;
}

// ---------------- kernel 3: output projection ------------------------------
__global__ __launch_bounds__(256) void k_oproj(
    const float* __restrict__ heads, const float* __restrict__ Wo,
    float* __restrict__ out) {
  __shared__ float Wl[128][128];
  __shared__ float inl[8][128];
  for (int e = threadIdx.x; e < 128 * 128; e += 256) Wl[e >> 7][e & 127] = Wo[e];
  const int r  = threadIdx.x >> 5;
  const int cg = (threadIdx.x & 31) << 2;
  const size_t rb = (size_t)blockIdx.x * 64;
  for (int pass = 0; pass < 8; ++pass) {
    __syncthreads();
    size_t row0 = rb + pass * 8;
    for (int e = threadIdx.x; e < 8 * 128; e += 256)
      inl[e >> 7][e & 127] = heads[(row0 + (e >> 7)) * 128 + (e & 127)];
    __syncthreads();
    f32x4 acc = {0.f, 0.f, 0.f, 0.f};
    #pragma unroll 8
    for (int i = 0; i < 128; ++i) acc += inl[r][i] * *(const f32x4*)&Wl[i][cg];
    *(f32x4*)(out + (row0 + r) * 128 + cg) = acc;
  }
}

// ---------------- launch ---------------------------------------------------
extern "C" void kernel_launch(void* const* d_in, const int* in_sizes, int n_in,
                              void* d_out, int out_size, void* d_ws, size_t ws_size,
                              hipStream_t stream) {
  const float* qin = (const float*)d_in[0];
  const float* hin = (const float*)d_in[1];
  const void* mask = d_in[2];
  const float* Wq  = (const float*)d_in[3];
  const float* Wk  = (const float*)d_in[4];
  const float* Wv  = (const float*)d_in[5];
  const float* Wo  = (const float*)d_in[6];
  float* out = (float*)d_out;
  char* ws = (char*)d_ws;

  const size_t MAT = (size_t)2 * SEQ * DIM;   // elems per bf16 matrix
  const size_t R   = (size_t)2 * SEQ;         // total rows

  // pick split factor by workspace budget (deterministic: ws_size is fixed)
  int NS = 4;
  while (NS > 1) {
    size_t need = 1024 + 3 * MAT * 2 + R * DIM * 4 +
                  (size_t)NS * (R * DIM * 4 + 2 * R * NHEADS * 4);
    if (need <= ws_size) break;
    NS >>= 1;
  }
  const int NT = 128 / NS;

  int* flag = (int*)ws;
  unsigned short* Qp    = (unsigned short*)(ws + 1024);
  unsigned short* Kp    = Qp + MAT;
  unsigned short* Vt    = Kp + MAT;
  float*          heads = (float*)(Vt + MAT);          // 4 MB
  float*          parts = heads + R * DIM;             // NS * 4 MB
  float*          Mb    = parts + (size_t)NS * R * DIM;
  float*          Lb    = Mb + (size_t)NS * R * NHEADS;

  k_detect<<<1, 64, 0, stream>>>((const unsigned*)mask, flag);
  k_proj<<<dim3(128, 3), 256, 0, stream>>>(qin, hin, Wq, Wk, Wv, Qp, Kp, Vt);
  k_flash<<<256 * NS, 512, 0, stream>>>(Qp, Kp, Vt, mask, flag, parts, Mb, Lb, NT);
  k_comb<<<R / 8, 256, 0, stream>>>(parts, Mb, Lb, heads, NS);
  k_oproj<<<128, 256, 0, stream>>>(heads, Wo, out);
}

// Round 5
// 213.061 us; speedup vs baseline: 1.7644x; 1.6681x over previous
//
#include <hip/hip_runtime.h>
#include <stdint.h>

#define SEQ 4096
#define DIM 128
#define NHEADS 8
#define HDK 16

typedef __bf16 bf16x2 __attribute__((ext_vector_type(2)));
typedef __bf16 bf16x8 __attribute__((ext_vector_type(8)));
typedef float f32x16 __attribute__((ext_vector_type(16)));
typedef float f32x4 __attribute__((ext_vector_type(4)));
typedef unsigned uint2v __attribute__((ext_vector_type(2)));
typedef unsigned uint4v __attribute__((ext_vector_type(4)));

__device__ inline unsigned short f2bf(float x) {
  unsigned u = __builtin_bit_cast(unsigned, x);
  u = (u + 0x7FFFu + ((u >> 16) & 1u)) >> 16;
  return (unsigned short)u;
}
__device__ inline unsigned pkbf(float lo, float hi) {
  return (unsigned)f2bf(lo) | ((unsigned)f2bf(hi) << 16);
}
// native RNE casts; compiler fuses pairs into v_cvt_pk_bf16_f32 (m240)
__device__ inline unsigned pkbf_fast(float lo, float hi) {
  bf16x2 t;
  t[0] = (__bf16)lo;
  t[1] = (__bf16)hi;
  return __builtin_bit_cast(unsigned, t);
}

// ---------------- kernel 0: mask dtype probe -------------------------------
__global__ void k_detect(const unsigned* __restrict__ mw, int* __restrict__ flag) {
  if (threadIdx.x == 0) {
    int words = 1;
    for (int i = 0; i < 32; ++i) {
      unsigned w = mw[i];
      if (!(w == 0u || w == 1u || w == 0x3F800000u)) words = 0;
    }
    *flag = words;
  }
}

// ---------------- kernel 1: input projections ------------------------------
__global__ __launch_bounds__(256) void k_proj(
    const float* __restrict__ qin, const float* __restrict__ hin,
    const float* __restrict__ Wq, const float* __restrict__ Wk, const float* __restrict__ Wv,
    unsigned short* __restrict__ Qp, unsigned short* __restrict__ Kp,
    unsigned short* __restrict__ Vt) {
  __shared__ float Wl[128][128];   // Wl[i][c], c = h*16+k
  __shared__ float inl[8][128];
  const int mat = blockIdx.y;
  const float* in = (mat == 0) ? qin : hin;
  const float* W  = (mat == 0) ? Wq : (mat == 1 ? Wk : Wv);
  for (int e = threadIdx.x; e < 128 * 128; e += 256) {
    int i = e >> 7, c = e & 127;   // W shape (8,128,16): [h][i][k]
    Wl[i][c] = W[((size_t)((c >> 4) * 128 + i)) * 16 + (c & 15)];
  }
  const int r  = threadIdx.x >> 5;
  const int cg = (threadIdx.x & 31) << 2;
  const size_t rb = (size_t)blockIdx.x * 64;
  const float SCALE_Q = 0.25f * 1.4426950408889634f;  // norm * log2(e)
  for (int pass = 0; pass < 8; ++pass) {
    __syncthreads();
    size_t row0 = rb + pass * 8;
    for (int e = threadIdx.x; e < 8 * 128; e += 256)
      inl[e >> 7][e & 127] = in[(row0 + (e >> 7)) * 128 + (e & 127)];
    __syncthreads();
    f32x4 acc = {0.f, 0.f, 0.f, 0.f};
    #pragma unroll 8
    for (int i = 0; i < 128; ++i) {
      float a = inl[r][i];
      acc += a * *(const f32x4*)&Wl[i][cg];
    }
    size_t grow = row0 + r;
    if (mat == 0) {
      uint2v o = { pkbf(acc[0] * SCALE_Q, acc[1] * SCALE_Q),
                   pkbf(acc[2] * SCALE_Q, acc[3] * SCALE_Q) };
      *(uint2v*)(Qp + grow * DIM + cg) = o;
    } else if (mat == 1) {
      uint2v o = { pkbf(acc[0], acc[1]), pkbf(acc[2], acc[3]) };
      *(uint2v*)(Kp + grow * DIM + cg) = o;
    } else {
      size_t b = grow >> 12, n = grow & 4095;
      #pragma unroll
      for (int j = 0; j < 4; ++j)
        Vt[(b * DIM + cg + j) * SEQ + n] = f2bf(acc[j]);
    }
  }
}

// ---------------- kernel 2: fused flash attention, split-K -----------------
// grid = 256*NS; block = 8 waves = 8 heads; sp covers KV tiles [sp*NT,(sp+1)*NT).
// launch_bounds (512,4): 128-VGPR cap -> NO spill (r4's (512,8) forced 64 and
// spilled ~930 MB of scratch to HBM -- that was the whole regression).
__global__ __launch_bounds__(512, 4) void k_flash(
    const unsigned short* __restrict__ Qp, const unsigned short* __restrict__ Kp,
    const unsigned short* __restrict__ Vt, const void* __restrict__ maskp,
    const int* __restrict__ flagp, float* __restrict__ parts,
    float* __restrict__ Mb, float* __restrict__ Lb, int NT) {
  __shared__ unsigned mbits[2][32];
  const int tid  = threadIdx.x;
  const int wv   = tid >> 6;
  const int lane = tid & 63;
  const int q    = lane & 31;
  const int hi   = lane >> 5;
  const int h    = wv;
  const int sp   = blockIdx.x >> 8;
  const int bqb  = blockIdx.x & 255;
  const int b    = bqb >> 7;
  const int qb   = (bqb & 127) << 5;
  const int kt0  = sp * NT;
  const int wordmode = *flagp;

  const bf16x8 qfrag =
      *(const bf16x8*)(Qp + ((size_t)b * SEQ + qb + q) * DIM + h * HDK + hi * 8);
  const unsigned short* kptr = Kp + ((size_t)b * SEQ) * DIM + h * HDK + hi * 8;
  const unsigned short* vptr = Vt + ((size_t)b * DIM + h * HDK + q) * SEQ + hi * 8;
  const bool vval = q < 16;   // A-operand guard: V channels 16..31 are zero

  const unsigned*      mw = (const unsigned*)maskp;
  const unsigned char* m8 = (const unsigned char*)maskp;
  const size_t mrowbase = (size_t)b * SEQ + qb;

  // ---- prefetch state: mask words (rows tid>>5 and 16+tid>>5) + K frag
  size_t gi0 = (mrowbase + (tid >> 5)) * SEQ + ((size_t)kt0 << 5) + (tid & 31);
  size_t gi1 = gi0 + (size_t)16 * SEQ;
  unsigned pv0, pv1;
  if (wordmode) { pv0 = mw[gi0]; pv1 = mw[gi1]; }
  else          { pv0 = m8[gi0]; pv1 = m8[gi1]; }
  bf16x8 kf = *(const bf16x8*)(kptr + (size_t)((kt0 << 5) + q) * DIM);

  f32x16 oacc = {};           // O^T: row = channel crow(r,hi), col = own q
  float m = -1e38f, lsum = 0.f;

  for (int t = 0; t < NT; ++t) {
    const int kvb = (kt0 + t) << 5;
    const int bf  = t & 1;
    // ---- ballot the prefetched mask words into packed row-bitmasks
    {
      unsigned long long bal = __ballot(pv0 != 0u);
      if (lane == 0) {
        mbits[bf][(wv << 1)]     = (unsigned)bal;
        mbits[bf][(wv << 1) + 1] = (unsigned)(bal >> 32);
      }
    }
    {
      unsigned long long bal = __ballot(pv1 != 0u);
      if (lane == 0) {
        mbits[bf][16 + (wv << 1)]     = (unsigned)bal;
        mbits[bf][16 + (wv << 1) + 1] = (unsigned)(bal >> 32);
      }
    }
    // ---- issue next tile's prefetch (mask + K) before the barrier
    const int adv = (t + 1 < NT) ? 32 : 0;
    gi0 += adv; gi1 += adv;
    if (wordmode) { pv0 = mw[gi0]; pv1 = mw[gi1]; }
    else          { pv0 = m8[gi0]; pv1 = m8[gi1]; }
    bf16x8 kfn = *(const bf16x8*)(kptr + (size_t)(kvb + adv + q) * DIM);
    __syncthreads();

    // ---- scores: S^T tile, column q per lane
    f32x16 z16 = {};
    f32x16 st = __builtin_amdgcn_mfma_f32_32x32x16_bf16(kf, qfrag, z16, 0, 0, 0);
    kf = kfn;

    const unsigned mrow = mbits[bf][q];
    float s[16];
    #pragma unroll
    for (int r = 0; r < 16; ++r) {
      const int kv = (r & 3) + 8 * (r >> 2) + (hi << 2);
      s[r] = ((mrow >> kv) & 1u) ? -3.0e38f : st[r];
    }
    // ---- online softmax in log2 domain (scale folded into Q)
    float tmax = s[0];
    #pragma unroll
    for (int r = 1; r < 16; ++r) tmax = fmaxf(tmax, s[r]);
    tmax = fmaxf(tmax, __shfl_xor(tmax, 32));

    const float newm = fmaxf(m, tmax);
    const float fs = exp2f(m - newm);   // per-lane scalar (col = own q)
    m = newm;
    lsum *= fs;
    #pragma unroll
    for (int r = 0; r < 16; ++r) oacc[r] *= fs;

    float p[16], ts = 0.f;
    #pragma unroll
    for (int r = 0; r < 16; ++r) { p[r] = exp2f(s[r] - m); ts += p[r]; }
    lsum += ts + __shfl_xor(ts, 32);

    // ---- PV: O^T += V^T_slice * P^T_slice  (two K=16 slices)
    #pragma unroll
    for (int sl = 0; sl < 2; ++sl) {
      unsigned a0 = pkbf_fast(p[8 * sl + 0], p[8 * sl + 1]);
      unsigned a1 = pkbf_fast(p[8 * sl + 2], p[8 * sl + 3]);
      unsigned b0 = pkbf_fast(p[8 * sl + 4], p[8 * sl + 5]);
      unsigned b1 = pkbf_fast(p[8 * sl + 6], p[8 * sl + 7]);
      unsigned pa0 = (unsigned)__shfl_xor((int)a0, 32);
      unsigned pa1 = (unsigned)__shfl_xor((int)a1, 32);
      unsigned pb0 = (unsigned)__shfl_xor((int)b0, 32);
      unsigned pb1 = (unsigned)__shfl_xor((int)b1, 32);
      uint4v w = { hi ? pb0 : a0, hi ? pb1 : a1, hi ? b0 : pa0, hi ? b1 : pa1 };
      bf16x8 pfrag = __builtin_bit_cast(bf16x8, w);
      bf16x8 vfrag = {};
      if (vval) vfrag = *(const bf16x8*)(vptr + kvb + sl * 16);
      oacc = __builtin_amdgcn_mfma_f32_32x32x16_bf16(vfrag, pfrag, oacc, 0, 0, 0);
    }
  }

  // ---- epilogue: unnormalized partial store; all lanes store own q column
  const size_t row = (size_t)b * SEQ + qb + q;
  float* hp = parts + ((size_t)sp * 2 * SEQ + row) * DIM + h * HDK;
  f32x4 w0 = { oacc[0], oacc[1], oacc[2], oacc[3] };
  f32x4 w1 = { oacc[4], oacc[5], oacc[6], oacc[7] };
  *(f32x4*)(hp + 4 * hi)     = w0;
  *(f32x4*)(hp + 8 + 4 * hi) = w1;
  if (hi == 0) {
    Mb[((size_t)sp * 2 * SEQ + row) * NHEADS + h] = m;
    Lb[((size_t)sp * 2 * SEQ + row) * NHEADS + h] = lsum;
  }
}

// ---------------- kernel 2b: split-K combine -------------------------------
__global__ __launch_bounds__(256) void k_comb(
    const float* __restrict__ parts, const float* __restrict__ Mb,
    const float* __restrict__ Lb, float* __restrict__ heads, int NS) {
  const size_t R = (size_t)2 * SEQ;
  const size_t row = (size_t)blockIdx.x * 8 + (threadIdx.x >> 5);
  const int cg = (threadIdx.x & 31) << 2;
  const int h  = cg >> 4;
  float mmax = -1e38f;
  for (int sp = 0; sp < NS; ++sp)
    mmax = fmaxf(mmax, Mb[(sp * R + row) * NHEADS + h]);
  float l = 0.f;
  f32x4 acc = {0.f, 0.f, 0.f, 0.f};
  for (int sp = 0; sp < NS; ++sp) {
    float w = exp2f(Mb[(sp * R + row) * NHEADS + h] - mmax);
    l += Lb[(sp * R + row) * NHEADS + h] * w;
    f32x4 p = *(const f32x4*)&parts[(sp * R + row) * DIM + cg];
    acc += p * w;
  }
  const float rinv = l > 0.f ? 1.0f / l : 0.f;
  acc *= rinv;
  *(f32x4*)&heads[row * DIM + cg] = acc;
}

// ---------------- kernel 3: output projection ------------------------------
__global__ __launch_bounds__(256) void k_oproj(
    const float* __restrict__ heads, const float* __restrict__ Wo,
    float* __restrict__ out) {
  __shared__ float Wl[128][128];
  __shared__ float inl[8][128];
  for (int e = threadIdx.x; e < 128 * 128; e += 256) Wl[e >> 7][e & 127] = Wo[e];
  const int r  = threadIdx.x >> 5;
  const int cg = (threadIdx.x & 31) << 2;
  const size_t rb = (size_t)blockIdx.x * 64;
  for (int pass = 0; pass < 8; ++pass) {
    __syncthreads();
    size_t row0 = rb + pass * 8;
    for (int e = threadIdx.x; e < 8 * 128; e += 256)
      inl[e >> 7][e & 127] = heads[(row0 + (e >> 7)) * 128 + (e & 127)];
    __syncthreads();
    f32x4 acc = {0.f, 0.f, 0.f, 0.f};
    #pragma unroll 8
    for (int i = 0; i < 128; ++i) acc += inl[r][i] * *(const f32x4*)&Wl[i][cg];
    *(f32x4*)(out + (row0 + r) * 128 + cg) = acc;
  }
}

// ---------------- launch ---------------------------------------------------
extern "C" void kernel_launch(void* const* d_in, const int* in_sizes, int n_in,
                              void* d_out, int out_size, void* d_ws, size_t ws_size,
                              hipStream_t stream) {
  const float* qin = (const float*)d_in[0];
  const float* hin = (const float*)d_in[1];
  const void* mask = d_in[2];
  const float* Wq  = (const float*)d_in[3];
  const float* Wk  = (const float*)d_in[4];
  const float* Wv  = (const float*)d_in[5];
  const float* Wo  = (const float*)d_in[6];
  float* out = (float*)d_out;
  char* ws = (char*)d_ws;

  const size_t MAT = (size_t)2 * SEQ * DIM;   // elems per bf16 matrix
  const size_t R   = (size_t)2 * SEQ;         // total rows

  // pick split factor by workspace budget (deterministic: ws_size is fixed)
  int NS = 4;
  while (NS > 1) {
    size_t need = 1024 + 3 * MAT * 2 + R * DIM * 4 +
                  (size_t)NS * (R * DIM * 4 + 2 * R * NHEADS * 4);
    if (need <= ws_size) break;
    NS >>= 1;
  }
  const int NT = 128 / NS;

  int* flag = (int*)ws;
  unsigned short* Qp    = (unsigned short*)(ws + 1024);
  unsigned short* Kp    = Qp + MAT;
  unsigned short* Vt    = Kp + MAT;
  float*          heads = (float*)(Vt + MAT);          // 4 MB
  float*          parts = heads + R * DIM;             // NS * 4 MB
  float*          Mb    = parts + (size_t)NS * R * DIM;
  float*          Lb    = Mb + (size_t)NS * R * NHEADS;

  k_detect<<<1, 64, 0, stream>>>((const unsigned*)mask, flag);
  k_proj<<<dim3(128, 3), 256, 0, stream>>>(qin, hin, Wq, Wk, Wv, Qp, Kp, Vt);
  k_flash<<<256 * NS, 512, 0, stream>>>(Qp, Kp, Vt, mask, flag, parts, Mb, Lb, NT);
  k_comb<<<R / 8, 256, 0, stream>>>(parts, Mb, Lb, heads, NS);
  k_oproj<<<128, 256, 0, stream>>>(heads, Wo, out);
}